// Round 2
// baseline (395.247 us; speedup 1.0000x reference)
//
#include <hip/hip_runtime.h>

typedef unsigned short u16;
typedef unsigned int u32;
typedef __attribute__((ext_vector_type(8))) short bf16x8;
typedef __attribute__((ext_vector_type(4))) float f32x4;
typedef __attribute__((ext_vector_type(4))) u32 u32x4;
typedef __attribute__((ext_vector_type(2))) u32 u32x2;

__device__ __forceinline__ u16 f2bf(float f) {
  u32 u = __builtin_bit_cast(u32, f);
  return (u16)((u + 0x7FFFu + ((u >> 16) & 1u)) >> 16);
}
__device__ __forceinline__ float bf2f(u16 b) {
  return __builtin_bit_cast(float, (u32)b << 16);
}

__device__ __forceinline__ float fexp2(float x) {
#if __has_builtin(__builtin_amdgcn_exp2f)
  return __builtin_amdgcn_exp2f(x);
#else
  return __expf(x * 0.6931471805599453f);
#endif
}

__device__ __forceinline__ void lds_async16(const void* g, void* l) {
  auto gp = reinterpret_cast<const __attribute__((address_space(1))) u32*>(
      reinterpret_cast<uintptr_t>(g));
  auto lp = reinterpret_cast<__attribute__((address_space(3))) u32*>(
      reinterpret_cast<uintptr_t>(l));
  __builtin_amdgcn_global_load_lds(gp, lp, 16, 0, 0);
}

// ---------------- fp32 -> bf16 convert (vec4) ----------------
__global__ void cvt_kernel(const float* __restrict__ in, u16* __restrict__ out, int n4) {
  int i = blockIdx.x * 256 + threadIdx.x;
  if (i < n4) {
    f32x4 v = *(const f32x4*)(in + (size_t)i * 4);
    u32x2 o;
    o[0] = (u32)f2bf(v[0]) | ((u32)f2bf(v[1]) << 16);
    o[1] = (u32)f2bf(v[2]) | ((u32)f2bf(v[3]) << 16);
    *(u32x2*)(out + (size_t)i * 4) = o;
  }
}

// ---------------- GEMM: C[m][n] = sum_k A[m][k]*B[n][k] + bias[n] ----------------
template <bool OUT_BF16>
__global__ __launch_bounds__(256) void gemm_bt_kernel(
    const u16* __restrict__ A, const u16* __restrict__ B,
    const float* __restrict__ bias, void* __restrict__ C,
    int M, int N, int K) {
  __shared__ u16 sA[128 * 32];
  __shared__ u16 sB[128 * 32];
  const int tid = threadIdx.x;
  const int m0 = blockIdx.x * 128;
  const int n0 = blockIdx.y * 128;
  const int w = tid >> 6;
  const int lane = tid & 63;
  const int wr = (w >> 1) * 64;
  const int wc = (w & 1) * 64;
  const int lm = lane & 15;
  const int lk = (lane >> 4) * 8;

  f32x4 acc[4][4] = {};

  const int srow = tid >> 2;
  const int ssub = (tid & 3) * 8;
  const u16* Ag = A + (size_t)(m0 + srow) * K + ssub;
  const u16* Bg = B + (size_t)(n0 + srow) * K + ssub;
  const size_t rstep = (size_t)64 * K;

  for (int k0 = 0; k0 < K; k0 += 32) {
    __syncthreads();
    lds_async16(Ag + k0, &sA[tid * 8]);
    lds_async16(Ag + rstep + k0, &sA[2048 + tid * 8]);
    lds_async16(Bg + k0, &sB[tid * 8]);
    lds_async16(Bg + rstep + k0, &sB[2048 + tid * 8]);
    __syncthreads();
    bf16x8 af[4], bfr[4];
#pragma unroll
    for (int i = 0; i < 4; ++i)
      af[i] = *(const bf16x8*)&sA[(wr + i * 16 + lm) * 32 + lk];
#pragma unroll
    for (int j = 0; j < 4; ++j)
      bfr[j] = *(const bf16x8*)&sB[(wc + j * 16 + lm) * 32 + lk];
#pragma unroll
    for (int i = 0; i < 4; ++i)
#pragma unroll
      for (int j = 0; j < 4; ++j)
        acc[i][j] = __builtin_amdgcn_mfma_f32_16x16x32_bf16(af[i], bfr[j], acc[i][j], 0, 0, 0);
  }

  const int r0 = (lane >> 4) * 4;
#pragma unroll
  for (int j = 0; j < 4; ++j) {
    const int n = n0 + wc + j * 16 + lm;
    const float bv = bias[n];
#pragma unroll
    for (int i = 0; i < 4; ++i) {
#pragma unroll
      for (int r = 0; r < 4; ++r) {
        const int m = m0 + wr + i * 16 + r0 + r;
        float v = acc[i][j][r] + bv;
        if (OUT_BF16)
          ((u16*)C)[(size_t)m * N + n] = f2bf(v);
        else
          ((float*)C)[(size_t)m * N + n] = v;
      }
    }
  }
}

// ---------------- fused per-(block,head) attention ----------------
// qkv: 33792 x 768 bf16 (q|k|v each 256 cols). o_ws: (256 blocks x 256 rows x 256 f) bf16.
// S^T compute (mfma(K,Q)) so P regs are 4 consecutive j -> b64 LDS writes.
// LDS: sVt 16896 + sP 20480 = 37376 B -> 4 blocks/CU, 16 waves/CU.
__global__ __launch_bounds__(256, 4) void attn_kernel(const u16* __restrict__ qkv,
                                                      u16* __restrict__ o_ws) {
  __shared__ u16 sVt[32 * 264];   // V transposed, stride 264 u16 (528B)
  __shared__ u16 sP[4 * 64 * 40]; // per-wave P tile: 64 rows x 40 u16 (80B stride, 16B-aligned)

  const int bid = blockIdx.x;
  const int n = bid >> 3;
  const int h = bid & 7;
  const int rowbase = (n >> 5) * 4224 + (n & 31) * 128;
  const int tid = threadIdx.x;
  const int w = tid >> 6;
  const int lane = tid & 63;
  const int lm = lane & 15;
  const int lg = lane >> 4;

  // stage V transposed for this head
#pragma unroll
  for (int it = 0; it < 4; ++it) {
    int c = it * 256 + tid;
    int row = c >> 2;
    int sub = (c & 3) * 8;
    const u16* gv = qkv + (size_t)(rowbase + row) * 768 + 512 + h * 32 + sub;
    u32x4 vv = *(const u32x4*)gv;
#pragma unroll
    for (int q = 0; q < 4; ++q) {
      sVt[(sub + 2 * q) * 264 + row] = (u16)(vv[q] & 0xFFFFu);
      sVt[(sub + 2 * q + 1) * 264 + row] = (u16)(vv[q] >> 16);
    }
  }

  // Q fragments straight from global (wave-private rows)
  bf16x8 qf[4];
#pragma unroll
  for (int rt = 0; rt < 4; ++rt) {
    int row = rowbase + w * 64 + rt * 16 + lm;
    qf[rt] = *(const bf16x8*)(qkv + (size_t)row * 768 + h * 32 + lg * 8);
  }

  __syncthreads();

  f32x4 oacc[4][2] = {};
  float lsum[4] = {0.f, 0.f, 0.f, 0.f};
  u16* myP = sP + w * (64 * 40);
  const float C1 = 0.25500035370494726f; // scale * log2(e)
  const float C2 = 1.4426950408889634f;  // log2(e)
  const int jq = lg * 4;

  for (int ch = 0; ch < 8; ++ch) {
    // K fragments from global (L2-resident; rows ch*32 + ct*16 + lm)
    bf16x8 kf[2];
#pragma unroll
    for (int ct = 0; ct < 2; ++ct)
      kf[ct] = *(const bf16x8*)(qkv +
          (size_t)(rowbase + ch * 32 + ct * 16 + lm) * 768 + 256 + h * 32 + lg * 8);

    // S^T = K * Q^T : lane holds i = lm, j = jq + r
    f32x4 st[2][4] = {};
#pragma unroll
    for (int ct = 0; ct < 2; ++ct)
#pragma unroll
      for (int rt = 0; rt < 4; ++rt)
        st[ct][rt] = __builtin_amdgcn_mfma_f32_16x16x32_bf16(kf[ct], qf[rt], st[ct][rt], 0, 0, 0);

    // P = exp(S*scale + band); band addend is wave-uniform per 16x16 tile
#pragma unroll
    for (int ct = 0; ct < 2; ++ct) {
#pragma unroll
      for (int rt = 0; rt < 4; ++rt) {
        const int D0 = w * 64 + rt * 16 - (ch * 32 + ct * 16); // wave-uniform
        f32x4 s = st[ct][rt];
        float p0, p1, p2, p3;
        if (D0 >= 16 && D0 <= 112) {        // fully in-band: +1 bias
          p0 = fexp2(__builtin_fmaf(s[0], C1, C2));
          p1 = fexp2(__builtin_fmaf(s[1], C1, C2));
          p2 = fexp2(__builtin_fmaf(s[2], C1, C2));
          p3 = fexp2(__builtin_fmaf(s[3], C1, C2));
        } else if (D0 == 0) {               // diagonal: in-band iff lm >= jq+r
          p0 = fexp2(__builtin_fmaf(s[0], C1, (lm >= jq + 0) ? C2 : 0.0f));
          p1 = fexp2(__builtin_fmaf(s[1], C1, (lm >= jq + 1) ? C2 : 0.0f));
          p2 = fexp2(__builtin_fmaf(s[2], C1, (lm >= jq + 2) ? C2 : 0.0f));
          p3 = fexp2(__builtin_fmaf(s[3], C1, (lm >= jq + 3) ? C2 : 0.0f));
        } else if (D0 == 128) {             // far edge: in-band iff lm < jq+r
          p0 = fexp2(__builtin_fmaf(s[0], C1, (lm < jq + 0) ? C2 : 0.0f));
          p1 = fexp2(__builtin_fmaf(s[1], C1, (lm < jq + 1) ? C2 : 0.0f));
          p2 = fexp2(__builtin_fmaf(s[2], C1, (lm < jq + 2) ? C2 : 0.0f));
          p3 = fexp2(__builtin_fmaf(s[3], C1, (lm < jq + 3) ? C2 : 0.0f));
        } else {                            // fully out of band: no bias
          p0 = fexp2(s[0] * C1);
          p1 = fexp2(s[1] * C1);
          p2 = fexp2(s[2] * C1);
          p3 = fexp2(s[3] * C1);
        }
        lsum[rt] += (p0 + p1) + (p2 + p3);
        // pack 4 consecutive-j bf16 (round-half-up) and one b64 LDS write
        u32 u0 = __builtin_bit_cast(u32, p0) + 0x8000u;
        u32 u1 = __builtin_bit_cast(u32, p1) + 0x8000u;
        u32 u2 = __builtin_bit_cast(u32, p2) + 0x8000u;
        u32 u3 = __builtin_bit_cast(u32, p3) + 0x8000u;
        u32x2 pk;
        pk[0] = __builtin_amdgcn_perm(u1, u0, 0x07060302u);
        pk[1] = __builtin_amdgcn_perm(u3, u2, 0x07060302u);
        *(u32x2*)&myP[(rt * 16 + lm) * 40 + ct * 16 + jq] = pk;
      }
    }

    // O += P * Vc (wave-private P: in-order LDS, no barrier needed)
    bf16x8 pf[4], vf[2];
#pragma unroll
    for (int rt = 0; rt < 4; ++rt)
      pf[rt] = *(const bf16x8*)&myP[(rt * 16 + lm) * 40 + lg * 8];
#pragma unroll
    for (int ctd = 0; ctd < 2; ++ctd)
      vf[ctd] = *(const bf16x8*)&sVt[(ctd * 16 + lm) * 264 + ch * 32 + lg * 8];
#pragma unroll
    for (int rt = 0; rt < 4; ++rt)
#pragma unroll
      for (int ctd = 0; ctd < 2; ++ctd)
        oacc[rt][ctd] = __builtin_amdgcn_mfma_f32_16x16x32_bf16(pf[rt], vf[ctd], oacc[rt][ctd], 0, 0, 0);
  }

  // softmax denominators: lane holds partial for i = rt*16+lm over its j quad;
  // reduce across the 4 quads (lanes lm, lm+16, lm+32, lm+48)
  float linv[4];
#pragma unroll
  for (int rt = 0; rt < 4; ++rt) {
    float v = lsum[rt];
    v += __shfl_xor(v, 16);
    v += __shfl_xor(v, 32);
    linv[rt] = 1.0f / v;
  }

  // normalize + store; O C-layout rows are i = rt*16 + lg*4 + r -> shfl the inverse
#pragma unroll
  for (int rt = 0; rt < 4; ++rt) {
#pragma unroll
    for (int r = 0; r < 4; ++r) {
      float inv = __shfl(linv[rt], jq + r);
      int i_g = w * 64 + rt * 16 + jq + r;
#pragma unroll
      for (int ctd = 0; ctd < 2; ++ctd) {
        float v = oacc[rt][ctd][r] * inv;
        u32 u = __builtin_bit_cast(u32, v) + 0x8000u;
        o_ws[((size_t)(n * 256 + i_g)) * 256 + h * 32 + ctd * 16 + lm] = (u16)(u >> 16);
      }
    }
  }
}

// ---------------- overlap-add combine: oc[t] = sum(covering o_ws)/cnt ----------------
__global__ void combine_kernel(const u16* __restrict__ o_ws, u16* __restrict__ oc) {
  int gid = blockIdx.x * 256 + threadIdx.x;
  int m = gid >> 5;             // global row (bc*4224 + t)
  int f0 = (gid & 31) << 3;     // 8 features per thread
  int bc = m / 4224;
  int t = m - bc * 4224;
  int i0 = t >> 7;
  float a[8] = {0.f, 0.f, 0.f, 0.f, 0.f, 0.f, 0.f, 0.f};
  if (i0 <= 31) {
    const u16* p = o_ws + ((size_t)((bc * 32 + i0) * 256 + (t - (i0 << 7)))) * 256 + f0;
    u32x4 v = *(const u32x4*)p;
#pragma unroll
    for (int q = 0; q < 4; ++q) {
      a[2 * q] += bf2f((u16)(v[q] & 0xFFFFu));
      a[2 * q + 1] += bf2f((u16)(v[q] >> 16));
    }
  }
  if (i0 >= 1) {
    int i1 = i0 - 1;
    const u16* p = o_ws + ((size_t)((bc * 32 + i1) * 256 + (t - (i1 << 7)))) * 256 + f0;
    u32x4 v = *(const u32x4*)p;
#pragma unroll
    for (int q = 0; q < 4; ++q) {
      a[2 * q] += bf2f((u16)(v[q] & 0xFFFFu));
      a[2 * q + 1] += bf2f((u16)(v[q] >> 16));
    }
  }
  float sc = (i0 >= 1 && i0 <= 31) ? 0.5f : 1.0f;
  u32x2 o;
  o[0] = (u32)f2bf(a[0] * sc) | ((u32)f2bf(a[1] * sc) << 16);
  o[1] = (u32)f2bf(a[2] * sc) | ((u32)f2bf(a[3] * sc) << 16);
  u32x2 o2;
  o2[0] = (u32)f2bf(a[4] * sc) | ((u32)f2bf(a[5] * sc) << 16);
  o2[1] = (u32)f2bf(a[6] * sc) | ((u32)f2bf(a[7] * sc) << 16);
  u16* dst = oc + (size_t)m * 256 + f0;
  *(u32x2*)dst = o;
  *(u32x2*)(dst + 4) = o2;
}

extern "C" void kernel_launch(void* const* d_in, const int* in_sizes, int n_in,
                              void* d_out, int out_size, void* d_ws, size_t ws_size,
                              hipStream_t stream) {
  const float* x = (const float*)d_in[0];
  const float* w_in = (const float*)d_in[1];
  const float* b_in = (const float*)d_in[2];
  const float* w_out = (const float*)d_in[3];
  const float* b_out = (const float*)d_in[4];
  float* y = (float*)d_out;
  char* ws = (char*)d_ws;

  // workspace layout (bytes)
  u16* qkv = (u16*)(ws);                   // 33792*768*2   = 51,904,512
  u16* xbf = (u16*)(ws + 51904512);        // 33792*256*2   = 17,301,504 (reused as oc)
  u16* ows = (u16*)(ws + 69206016);        // 256*256*256*2 = 33,554,432
  u16* winb = (u16*)(ws + 102760448);      // 768*256*2     = 393,216
  u16* woutb = (u16*)(ws + 103153664);     // 256*256*2     = 131,072  (end 103,284,736)

  cvt_kernel<<<8448, 256, 0, stream>>>(x, xbf, 2162688);
  cvt_kernel<<<192, 256, 0, stream>>>(w_in, winb, 49152);
  cvt_kernel<<<64, 256, 0, stream>>>(w_out, woutb, 16384);

  // qkv = x @ w_in^T + b_in  (once per row; overlapping blocks share rows)
  gemm_bt_kernel<true><<<dim3(264, 6), 256, 0, stream>>>(xbf, winb, b_in, qkv, 33792, 768, 256);

  // per-(block, head) attention
  attn_kernel<<<2048, 256, 0, stream>>>(qkv, ows);

  // overlap-add + count division (commutes with the linear w_out projection)
  combine_kernel<<<4224, 256, 0, stream>>>(ows, xbf);

  // y = oc @ w_out^T + b_out
  gemm_bt_kernel<false><<<dim3(264, 2), 256, 0, stream>>>(xbf, woutb, b_out, y, 33792, 256, 256);
}

// Round 3
// 260.393 us; speedup vs baseline: 1.5179x; 1.5179x over previous
//
#include <hip/hip_runtime.h>

typedef unsigned short u16;
typedef unsigned int u32;
typedef __attribute__((ext_vector_type(8))) short bf16x8;
typedef __attribute__((ext_vector_type(4))) float f32x4;
typedef __attribute__((ext_vector_type(4))) u32 u32x4;
typedef __attribute__((ext_vector_type(2))) u32 u32x2;

__device__ __forceinline__ u16 f2bf(float f) {
  u32 u = __builtin_bit_cast(u32, f);
  return (u16)((u + 0x7FFFu + ((u >> 16) & 1u)) >> 16);
}
__device__ __forceinline__ float bf2f(u16 b) {
  return __builtin_bit_cast(float, (u32)b << 16);
}

__device__ __forceinline__ float fexp2(float x) {
#if __has_builtin(__builtin_amdgcn_exp2f)
  return __builtin_amdgcn_exp2f(x);
#else
  return __expf(x * 0.6931471805599453f);
#endif
}

__device__ __forceinline__ void lds_async16(const void* g, void* l) {
  auto gp = reinterpret_cast<const __attribute__((address_space(1))) u32*>(
      reinterpret_cast<uintptr_t>(g));
  auto lp = reinterpret_cast<__attribute__((address_space(3))) u32*>(
      reinterpret_cast<uintptr_t>(l));
  __builtin_amdgcn_global_load_lds(gp, lp, 16, 0, 0);
}

// ---------------- fp32 -> bf16 convert (vec4) ----------------
__global__ void cvt_kernel(const float* __restrict__ in, u16* __restrict__ out, int n4) {
  int i = blockIdx.x * 256 + threadIdx.x;
  if (i < n4) {
    f32x4 v = *(const f32x4*)(in + (size_t)i * 4);
    u32x2 o;
    o[0] = (u32)f2bf(v[0]) | ((u32)f2bf(v[1]) << 16);
    o[1] = (u32)f2bf(v[2]) | ((u32)f2bf(v[3]) << 16);
    *(u32x2*)(out + (size_t)i * 4) = o;
  }
}

// ---------------- GEMM: C[m][n] = sum_k A[m][k]*B[n][k] + bias[n] ----------------
template <bool OUT_BF16>
__global__ __launch_bounds__(256) void gemm_bt_kernel(
    const u16* __restrict__ A, const u16* __restrict__ B,
    const float* __restrict__ bias, void* __restrict__ C,
    int M, int N, int K) {
  __shared__ u16 sA[128 * 32];
  __shared__ u16 sB[128 * 32];
  const int tid = threadIdx.x;
  const int m0 = blockIdx.x * 128;
  const int n0 = blockIdx.y * 128;
  const int w = tid >> 6;
  const int lane = tid & 63;
  const int wr = (w >> 1) * 64;
  const int wc = (w & 1) * 64;
  const int lm = lane & 15;
  const int lk = (lane >> 4) * 8;

  f32x4 acc[4][4] = {};

  const int srow = tid >> 2;
  const int ssub = (tid & 3) * 8;
  const u16* Ag = A + (size_t)(m0 + srow) * K + ssub;
  const u16* Bg = B + (size_t)(n0 + srow) * K + ssub;
  const size_t rstep = (size_t)64 * K;

  for (int k0 = 0; k0 < K; k0 += 32) {
    __syncthreads();
    lds_async16(Ag + k0, &sA[tid * 8]);
    lds_async16(Ag + rstep + k0, &sA[2048 + tid * 8]);
    lds_async16(Bg + k0, &sB[tid * 8]);
    lds_async16(Bg + rstep + k0, &sB[2048 + tid * 8]);
    __syncthreads();
    bf16x8 af[4], bfr[4];
#pragma unroll
    for (int i = 0; i < 4; ++i)
      af[i] = *(const bf16x8*)&sA[(wr + i * 16 + lm) * 32 + lk];
#pragma unroll
    for (int j = 0; j < 4; ++j)
      bfr[j] = *(const bf16x8*)&sB[(wc + j * 16 + lm) * 32 + lk];
#pragma unroll
    for (int i = 0; i < 4; ++i)
#pragma unroll
      for (int j = 0; j < 4; ++j)
        acc[i][j] = __builtin_amdgcn_mfma_f32_16x16x32_bf16(af[i], bfr[j], acc[i][j], 0, 0, 0);
  }

  const int r0 = (lane >> 4) * 4;
#pragma unroll
  for (int j = 0; j < 4; ++j) {
    const int n = n0 + wc + j * 16 + lm;
    const float bv = bias[n];
#pragma unroll
    for (int i = 0; i < 4; ++i) {
#pragma unroll
      for (int r = 0; r < 4; ++r) {
        const int m = m0 + wr + i * 16 + r0 + r;
        float v = acc[i][j][r] + bv;
        if (OUT_BF16)
          ((u16*)C)[(size_t)m * N + n] = f2bf(v);
        else
          ((float*)C)[(size_t)m * N + n] = v;
      }
    }
  }
}

// ---------------- fused per-(block,head) attention ----------------
// qkv: 33792 x 768 bf16 (q|k|v each 256 cols). o_ws: (256 blocks x 256 rows x 256 f) bf16.
// S^T compute (mfma(K,Q)) so P regs are 4 consecutive j -> b64 LDS writes.
// LDS: sVt 16896 + sP 20480 = 37376 B -> 4 blocks/CU LDS-wise.
// launch_bounds(256,2): VGPR cap 256 — the (256,4) variant capped arch-VGPRs at 64
// and spilled to scratch (FETCH 281MB / WRITE 432MB, 250us). Do NOT tighten.
__global__ __launch_bounds__(256, 2) void attn_kernel(const u16* __restrict__ qkv,
                                                      u16* __restrict__ o_ws) {
  __shared__ u16 sVt[32 * 264];   // V transposed, stride 264 u16 (528B)
  __shared__ u16 sP[4 * 64 * 40]; // per-wave P tile: 64 rows x 40 u16 (80B stride, 16B-aligned)

  const int bid = blockIdx.x;
  const int n = bid >> 3;
  const int h = bid & 7;
  const int rowbase = (n >> 5) * 4224 + (n & 31) * 128;
  const int tid = threadIdx.x;
  const int w = tid >> 6;
  const int lane = tid & 63;
  const int lm = lane & 15;
  const int lg = lane >> 4;

  // stage V transposed for this head
#pragma unroll
  for (int it = 0; it < 4; ++it) {
    int c = it * 256 + tid;
    int row = c >> 2;
    int sub = (c & 3) * 8;
    const u16* gv = qkv + (size_t)(rowbase + row) * 768 + 512 + h * 32 + sub;
    u32x4 vv = *(const u32x4*)gv;
#pragma unroll
    for (int q = 0; q < 4; ++q) {
      sVt[(sub + 2 * q) * 264 + row] = (u16)(vv[q] & 0xFFFFu);
      sVt[(sub + 2 * q + 1) * 264 + row] = (u16)(vv[q] >> 16);
    }
  }

  // Q fragments straight from global (wave-private rows; 16 rows x 64B contiguous)
  bf16x8 qf[4];
#pragma unroll
  for (int rt = 0; rt < 4; ++rt) {
    int row = rowbase + w * 64 + rt * 16 + lm;
    qf[rt] = *(const bf16x8*)(qkv + (size_t)row * 768 + h * 32 + lg * 8);
  }

  __syncthreads();

  f32x4 oacc[4][2] = {};
  float lsum[4] = {0.f, 0.f, 0.f, 0.f};
  u16* myP = sP + w * (64 * 40);
  const float C1 = 0.25500035370494726f; // scale * log2(e)
  const float C2 = 1.4426950408889634f;  // log2(e)
  const int jq = lg * 4;

  for (int ch = 0; ch < 8; ++ch) {
    // one 16-col K tile at a time: halves live score registers vs st[2][4]
#pragma unroll
    for (int ct = 0; ct < 2; ++ct) {
      bf16x8 kf = *(const bf16x8*)(qkv +
          (size_t)(rowbase + ch * 32 + ct * 16 + lm) * 768 + 256 + h * 32 + lg * 8);

      // S^T = K * Q^T : lane holds i = lm, j = jq + r
      f32x4 st[4] = {};
#pragma unroll
      for (int rt = 0; rt < 4; ++rt)
        st[rt] = __builtin_amdgcn_mfma_f32_16x16x32_bf16(kf, qf[rt], st[rt], 0, 0, 0);

      // P = exp(S*scale + band); band addend is wave-uniform per 16x16 tile
#pragma unroll
      for (int rt = 0; rt < 4; ++rt) {
        const int D0 = w * 64 + rt * 16 - (ch * 32 + ct * 16); // wave-uniform
        f32x4 s = st[rt];
        float p0, p1, p2, p3;
        if (D0 >= 16 && D0 <= 112) {        // fully in-band: +1 bias
          p0 = fexp2(__builtin_fmaf(s[0], C1, C2));
          p1 = fexp2(__builtin_fmaf(s[1], C1, C2));
          p2 = fexp2(__builtin_fmaf(s[2], C1, C2));
          p3 = fexp2(__builtin_fmaf(s[3], C1, C2));
        } else if (D0 == 0) {               // diagonal: in-band iff lm >= jq+r
          p0 = fexp2(__builtin_fmaf(s[0], C1, (lm >= jq + 0) ? C2 : 0.0f));
          p1 = fexp2(__builtin_fmaf(s[1], C1, (lm >= jq + 1) ? C2 : 0.0f));
          p2 = fexp2(__builtin_fmaf(s[2], C1, (lm >= jq + 2) ? C2 : 0.0f));
          p3 = fexp2(__builtin_fmaf(s[3], C1, (lm >= jq + 3) ? C2 : 0.0f));
        } else if (D0 == 128) {             // far edge: in-band iff lm < jq+r
          p0 = fexp2(__builtin_fmaf(s[0], C1, (lm < jq + 0) ? C2 : 0.0f));
          p1 = fexp2(__builtin_fmaf(s[1], C1, (lm < jq + 1) ? C2 : 0.0f));
          p2 = fexp2(__builtin_fmaf(s[2], C1, (lm < jq + 2) ? C2 : 0.0f));
          p3 = fexp2(__builtin_fmaf(s[3], C1, (lm < jq + 3) ? C2 : 0.0f));
        } else {                            // fully out of band: no bias
          p0 = fexp2(s[0] * C1);
          p1 = fexp2(s[1] * C1);
          p2 = fexp2(s[2] * C1);
          p3 = fexp2(s[3] * C1);
        }
        lsum[rt] += (p0 + p1) + (p2 + p3);
        // pack 4 consecutive-j bf16 (round-half-up) and one b64 LDS write
        u32 u0 = __builtin_bit_cast(u32, p0) + 0x8000u;
        u32 u1 = __builtin_bit_cast(u32, p1) + 0x8000u;
        u32 u2 = __builtin_bit_cast(u32, p2) + 0x8000u;
        u32 u3 = __builtin_bit_cast(u32, p3) + 0x8000u;
        u32x2 pk;
        pk[0] = __builtin_amdgcn_perm(u1, u0, 0x07060302u);
        pk[1] = __builtin_amdgcn_perm(u3, u2, 0x07060302u);
        *(u32x2*)&myP[(rt * 16 + lm) * 40 + ct * 16 + jq] = pk;
      }
    }

    // O += P * Vc (wave-private P: in-order LDS, no barrier needed)
    bf16x8 pf[4], vf[2];
#pragma unroll
    for (int rt = 0; rt < 4; ++rt)
      pf[rt] = *(const bf16x8*)&myP[(rt * 16 + lm) * 40 + lg * 8];
#pragma unroll
    for (int ctd = 0; ctd < 2; ++ctd)
      vf[ctd] = *(const bf16x8*)&sVt[(ctd * 16 + lm) * 264 + ch * 32 + lg * 8];
#pragma unroll
    for (int rt = 0; rt < 4; ++rt)
#pragma unroll
      for (int ctd = 0; ctd < 2; ++ctd)
        oacc[rt][ctd] = __builtin_amdgcn_mfma_f32_16x16x32_bf16(pf[rt], vf[ctd], oacc[rt][ctd], 0, 0, 0);
  }

  // softmax denominators: lane holds partial for i = rt*16+lm over its j quad;
  // reduce across the 4 quads (lanes lm, lm+16, lm+32, lm+48)
  float linv[4];
#pragma unroll
  for (int rt = 0; rt < 4; ++rt) {
    float v = lsum[rt];
    v += __shfl_xor(v, 16);
    v += __shfl_xor(v, 32);
    linv[rt] = 1.0f / v;
  }

  // normalize + store; O C-layout rows are i = rt*16 + lg*4 + r -> shfl the inverse
#pragma unroll
  for (int rt = 0; rt < 4; ++rt) {
#pragma unroll
    for (int r = 0; r < 4; ++r) {
      float inv = __shfl(linv[rt], jq + r);
      int i_g = w * 64 + rt * 16 + jq + r;
#pragma unroll
      for (int ctd = 0; ctd < 2; ++ctd) {
        float v = oacc[rt][ctd][r] * inv;
        u32 u = __builtin_bit_cast(u32, v) + 0x8000u;
        o_ws[((size_t)(n * 256 + i_g)) * 256 + h * 32 + ctd * 16 + lm] = (u16)(u >> 16);
      }
    }
  }
}

// ---------------- overlap-add combine: oc[t] = sum(covering o_ws)/cnt ----------------
__global__ void combine_kernel(const u16* __restrict__ o_ws, u16* __restrict__ oc) {
  int gid = blockIdx.x * 256 + threadIdx.x;
  int m = gid >> 5;             // global row (bc*4224 + t)
  int f0 = (gid & 31) << 3;     // 8 features per thread
  int bc = m / 4224;
  int t = m - bc * 4224;
  int i0 = t >> 7;
  float a[8] = {0.f, 0.f, 0.f, 0.f, 0.f, 0.f, 0.f, 0.f};
  if (i0 <= 31) {
    const u16* p = o_ws + ((size_t)((bc * 32 + i0) * 256 + (t - (i0 << 7)))) * 256 + f0;
    u32x4 v = *(const u32x4*)p;
#pragma unroll
    for (int q = 0; q < 4; ++q) {
      a[2 * q] += bf2f((u16)(v[q] & 0xFFFFu));
      a[2 * q + 1] += bf2f((u16)(v[q] >> 16));
    }
  }
  if (i0 >= 1) {
    int i1 = i0 - 1;
    const u16* p = o_ws + ((size_t)((bc * 32 + i1) * 256 + (t - (i1 << 7)))) * 256 + f0;
    u32x4 v = *(const u32x4*)p;
#pragma unroll
    for (int q = 0; q < 4; ++q) {
      a[2 * q] += bf2f((u16)(v[q] & 0xFFFFu));
      a[2 * q + 1] += bf2f((u16)(v[q] >> 16));
    }
  }
  float sc = (i0 >= 1 && i0 <= 31) ? 0.5f : 1.0f;
  u32x2 o;
  o[0] = (u32)f2bf(a[0] * sc) | ((u32)f2bf(a[1] * sc) << 16);
  o[1] = (u32)f2bf(a[2] * sc) | ((u32)f2bf(a[3] * sc) << 16);
  u32x2 o2;
  o2[0] = (u32)f2bf(a[4] * sc) | ((u32)f2bf(a[5] * sc) << 16);
  o2[1] = (u32)f2bf(a[6] * sc) | ((u32)f2bf(a[7] * sc) << 16);
  u16* dst = oc + (size_t)m * 256 + f0;
  *(u32x2*)dst = o;
  *(u32x2*)(dst + 4) = o2;
}

extern "C" void kernel_launch(void* const* d_in, const int* in_sizes, int n_in,
                              void* d_out, int out_size, void* d_ws, size_t ws_size,
                              hipStream_t stream) {
  const float* x = (const float*)d_in[0];
  const float* w_in = (const float*)d_in[1];
  const float* b_in = (const float*)d_in[2];
  const float* w_out = (const float*)d_in[3];
  const float* b_out = (const float*)d_in[4];
  float* y = (float*)d_out;
  char* ws = (char*)d_ws;

  // workspace layout (bytes)
  u16* qkv = (u16*)(ws);                   // 33792*768*2   = 51,904,512
  u16* xbf = (u16*)(ws + 51904512);        // 33792*256*2   = 17,301,504 (reused as oc)
  u16* ows = (u16*)(ws + 69206016);        // 256*256*256*2 = 33,554,432
  u16* winb = (u16*)(ws + 102760448);      // 768*256*2     = 393,216
  u16* woutb = (u16*)(ws + 103153664);     // 256*256*2     = 131,072  (end 103,284,736)

  cvt_kernel<<<8448, 256, 0, stream>>>(x, xbf, 2162688);
  cvt_kernel<<<192, 256, 0, stream>>>(w_in, winb, 49152);
  cvt_kernel<<<64, 256, 0, stream>>>(w_out, woutb, 16384);

  // qkv = x @ w_in^T + b_in  (once per row; overlapping blocks share rows)
  gemm_bt_kernel<true><<<dim3(264, 6), 256, 0, stream>>>(xbf, winb, b_in, qkv, 33792, 768, 256);

  // per-(block, head) attention
  attn_kernel<<<2048, 256, 0, stream>>>(qkv, ows);

  // overlap-add + count division (commutes with the linear w_out projection)
  combine_kernel<<<4224, 256, 0, stream>>>(ows, xbf);

  // y = oc @ w_out^T + b_out
  gemm_bt_kernel<false><<<dim3(264, 2), 256, 0, stream>>>(xbf, woutb, b_out, y, 33792, 256, 256);
}

// Round 4
// 189.154 us; speedup vs baseline: 2.0896x; 1.3766x over previous
//
#include <hip/hip_runtime.h>

typedef unsigned short u16;
typedef unsigned int u32;
typedef __attribute__((ext_vector_type(8))) short bf16x8;
typedef __attribute__((ext_vector_type(4))) float f32x4;
typedef __attribute__((ext_vector_type(4))) u32 u32x4;
typedef __attribute__((ext_vector_type(2))) u32 u32x2;

__device__ __forceinline__ u16 f2bf(float f) {
  u32 u = __builtin_bit_cast(u32, f);
  return (u16)((u + 0x7FFFu + ((u >> 16) & 1u)) >> 16);
}
__device__ __forceinline__ float bf2f(u16 b) {
  return __builtin_bit_cast(float, (u32)b << 16);
}

__device__ __forceinline__ float fexp2(float x) {
#if __has_builtin(__builtin_amdgcn_exp2f)
  return __builtin_amdgcn_exp2f(x);
#else
  return __expf(x * 0.6931471805599453f);
#endif
}

__device__ __forceinline__ void lds_async16(const void* g, void* l) {
  auto gp = reinterpret_cast<const __attribute__((address_space(1))) u32*>(
      reinterpret_cast<uintptr_t>(g));
  auto lp = reinterpret_cast<__attribute__((address_space(3))) u32*>(
      reinterpret_cast<uintptr_t>(l));
  __builtin_amdgcn_global_load_lds(gp, lp, 16, 0, 0);
}

// ---------------- fp32 -> bf16 convert (vec4) ----------------
__global__ void cvt_kernel(const float* __restrict__ in, u16* __restrict__ out, int n4) {
  int i = blockIdx.x * 256 + threadIdx.x;
  if (i < n4) {
    f32x4 v = *(const f32x4*)(in + (size_t)i * 4);
    u32x2 o;
    o[0] = (u32)f2bf(v[0]) | ((u32)f2bf(v[1]) << 16);
    o[1] = (u32)f2bf(v[2]) | ((u32)f2bf(v[3]) << 16);
    *(u32x2*)(out + (size_t)i * 4) = o;
  }
}

// ---------------- GEMM: C[m][n] = sum_k A[m][k]*B[n][k] + bias[n] ----------------
template <bool OUT_BF16>
__global__ __launch_bounds__(256) void gemm_bt_kernel(
    const u16* __restrict__ A, const u16* __restrict__ B,
    const float* __restrict__ bias, void* __restrict__ C,
    int M, int N, int K) {
  __shared__ u16 sA[128 * 32];
  __shared__ u16 sB[128 * 32];
  const int tid = threadIdx.x;
  const int m0 = blockIdx.x * 128;
  const int n0 = blockIdx.y * 128;
  const int w = tid >> 6;
  const int lane = tid & 63;
  const int wr = (w >> 1) * 64;
  const int wc = (w & 1) * 64;
  const int lm = lane & 15;
  const int lk = (lane >> 4) * 8;

  f32x4 acc[4][4] = {};

  const int srow = tid >> 2;
  const int ssub = (tid & 3) * 8;
  const u16* Ag = A + (size_t)(m0 + srow) * K + ssub;
  const u16* Bg = B + (size_t)(n0 + srow) * K + ssub;
  const size_t rstep = (size_t)64 * K;

  for (int k0 = 0; k0 < K; k0 += 32) {
    __syncthreads();
    lds_async16(Ag + k0, &sA[tid * 8]);
    lds_async16(Ag + rstep + k0, &sA[2048 + tid * 8]);
    lds_async16(Bg + k0, &sB[tid * 8]);
    lds_async16(Bg + rstep + k0, &sB[2048 + tid * 8]);
    __syncthreads();
    bf16x8 af[4], bfr[4];
#pragma unroll
    for (int i = 0; i < 4; ++i)
      af[i] = *(const bf16x8*)&sA[(wr + i * 16 + lm) * 32 + lk];
#pragma unroll
    for (int j = 0; j < 4; ++j)
      bfr[j] = *(const bf16x8*)&sB[(wc + j * 16 + lm) * 32 + lk];
#pragma unroll
    for (int i = 0; i < 4; ++i)
#pragma unroll
      for (int j = 0; j < 4; ++j)
        acc[i][j] = __builtin_amdgcn_mfma_f32_16x16x32_bf16(af[i], bfr[j], acc[i][j], 0, 0, 0);
  }

  const int r0 = (lane >> 4) * 4;
#pragma unroll
  for (int j = 0; j < 4; ++j) {
    const int n = n0 + wc + j * 16 + lm;
    const float bv = bias[n];
#pragma unroll
    for (int i = 0; i < 4; ++i) {
#pragma unroll
      for (int r = 0; r < 4; ++r) {
        const int m = m0 + wr + i * 16 + r0 + r;
        float v = acc[i][j][r] + bv;
        if (OUT_BF16)
          ((u16*)C)[(size_t)m * N + n] = f2bf(v);
        else
          ((float*)C)[(size_t)m * N + n] = v;
      }
    }
  }
}

// ---------------- fused per-(block,head) attention ----------------
// qkv: 33792 x 768 bf16 (q|k|v each 256 cols). o_ws: (256 blocks x 256 rows x 256 f) bf16.
// S^T compute (mfma(K,Q)) so P regs are 4 consecutive j -> b64 LDS writes.
// LDS: sVt 16896 + sP 20480 = 37376 B.
// launch_bounds(256,2): VGPR budget 256/wave. The (256,4) variant spilled
// catastrophically (WRITE 432MB). Round-3 lesson: WITHOUT `#pragma unroll 1`
// the compiler fully unrolls the 8-iter ch loop, hoists all 16 kf loads, and
// spills (~118MB scratch writes, VGPR pinned at 128). Keep the unroll guard.
__global__ __launch_bounds__(256, 2) void attn_kernel(const u16* __restrict__ qkv,
                                                      u16* __restrict__ o_ws) {
  __shared__ u16 sVt[32 * 264];   // V transposed, stride 264 u16 (528B)
  __shared__ u16 sP[4 * 64 * 40]; // per-wave P tile: 64 rows x 40 u16 (80B stride, 16B-aligned)

  const int bid = blockIdx.x;
  const int n = bid >> 3;
  const int h = bid & 7;
  const int rowbase = (n >> 5) * 4224 + (n & 31) * 128;
  const int tid = threadIdx.x;
  const int w = tid >> 6;
  const int lane = tid & 63;
  const int lm = lane & 15;
  const int lg = lane >> 4;

  // stage V transposed for this head
#pragma unroll
  for (int it = 0; it < 4; ++it) {
    int c = it * 256 + tid;
    int row = c >> 2;
    int sub = (c & 3) * 8;
    const u16* gv = qkv + (size_t)(rowbase + row) * 768 + 512 + h * 32 + sub;
    u32x4 vv = *(const u32x4*)gv;
#pragma unroll
    for (int q = 0; q < 4; ++q) {
      sVt[(sub + 2 * q) * 264 + row] = (u16)(vv[q] & 0xFFFFu);
      sVt[(sub + 2 * q + 1) * 264 + row] = (u16)(vv[q] >> 16);
    }
  }

  // Q fragments straight from global (wave-private rows; 16 rows x 64B contiguous)
  bf16x8 qf[4];
#pragma unroll
  for (int rt = 0; rt < 4; ++rt) {
    int row = rowbase + w * 64 + rt * 16 + lm;
    qf[rt] = *(const bf16x8*)(qkv + (size_t)row * 768 + h * 32 + lg * 8);
  }

  __syncthreads();

  f32x4 oacc[4][2] = {};
  float lsum[4] = {0.f, 0.f, 0.f, 0.f};
  u16* myP = sP + w * (64 * 40);
  const float C1 = 0.25500035370494726f; // scale * log2(e)
  const float C2 = 1.4426950408889634f;  // log2(e)
  const int jq = lg * 4;
  // hoisted K base: row (rowbase + lm), K column block of this head
  const u16* kbase = qkv + (size_t)(rowbase + lm) * 768 + 256 + h * 32 + lg * 8;
  const int D0w = w * 64; // wave-uniform row offset

#pragma unroll 1
  for (int ch = 0; ch < 8; ++ch) {
    // one 16-col K tile at a time: halves live score registers vs st[2][4]
#pragma unroll
    for (int ct = 0; ct < 2; ++ct) {
      bf16x8 kf = *(const bf16x8*)(kbase + (size_t)(ch * 32 + ct * 16) * 768);

      // S^T = K * Q^T : lane holds i = lm (Q row), j = jq + r (K row)
      f32x4 st[4] = {};
#pragma unroll
      for (int rt = 0; rt < 4; ++rt)
        st[rt] = __builtin_amdgcn_mfma_f32_16x16x32_bf16(kf, qf[rt], st[rt], 0, 0, 0);

      // P = exp(S*scale + band); band addend is wave-uniform per 16x16 tile
#pragma unroll
      for (int rt = 0; rt < 4; ++rt) {
        const int D0 = D0w + rt * 16 - (ch * 32 + ct * 16); // wave-uniform
        f32x4 s = st[rt];
        float p0, p1, p2, p3;
        if (D0 >= 16 && D0 <= 112) {        // fully in-band: +1 bias
          p0 = fexp2(__builtin_fmaf(s[0], C1, C2));
          p1 = fexp2(__builtin_fmaf(s[1], C1, C2));
          p2 = fexp2(__builtin_fmaf(s[2], C1, C2));
          p3 = fexp2(__builtin_fmaf(s[3], C1, C2));
        } else if (D0 == 0) {               // diagonal: in-band iff lm >= jq+r
          p0 = fexp2(__builtin_fmaf(s[0], C1, (lm >= jq + 0) ? C2 : 0.0f));
          p1 = fexp2(__builtin_fmaf(s[1], C1, (lm >= jq + 1) ? C2 : 0.0f));
          p2 = fexp2(__builtin_fmaf(s[2], C1, (lm >= jq + 2) ? C2 : 0.0f));
          p3 = fexp2(__builtin_fmaf(s[3], C1, (lm >= jq + 3) ? C2 : 0.0f));
        } else if (D0 == 128) {             // far edge: in-band iff lm < jq+r
          p0 = fexp2(__builtin_fmaf(s[0], C1, (lm < jq + 0) ? C2 : 0.0f));
          p1 = fexp2(__builtin_fmaf(s[1], C1, (lm < jq + 1) ? C2 : 0.0f));
          p2 = fexp2(__builtin_fmaf(s[2], C1, (lm < jq + 2) ? C2 : 0.0f));
          p3 = fexp2(__builtin_fmaf(s[3], C1, (lm < jq + 3) ? C2 : 0.0f));
        } else {                            // fully out of band: no bias
          p0 = fexp2(s[0] * C1);
          p1 = fexp2(s[1] * C1);
          p2 = fexp2(s[2] * C1);
          p3 = fexp2(s[3] * C1);
        }
        lsum[rt] += (p0 + p1) + (p2 + p3);
        // pack 4 consecutive-j bf16 (round-half-up) and one b64 LDS write
        u32 u0 = __builtin_bit_cast(u32, p0) + 0x8000u;
        u32 u1 = __builtin_bit_cast(u32, p1) + 0x8000u;
        u32 u2 = __builtin_bit_cast(u32, p2) + 0x8000u;
        u32 u3 = __builtin_bit_cast(u32, p3) + 0x8000u;
        u32x2 pk;
        pk[0] = __builtin_amdgcn_perm(u1, u0, 0x07060302u);
        pk[1] = __builtin_amdgcn_perm(u3, u2, 0x07060302u);
        *(u32x2*)&myP[(rt * 16 + lm) * 40 + ct * 16 + jq] = pk;
      }
    }

    // O += P * Vc (wave-private P: in-order LDS, no barrier needed)
    bf16x8 pf[4], vf[2];
#pragma unroll
    for (int rt = 0; rt < 4; ++rt)
      pf[rt] = *(const bf16x8*)&myP[(rt * 16 + lm) * 40 + lg * 8];
#pragma unroll
    for (int ctd = 0; ctd < 2; ++ctd)
      vf[ctd] = *(const bf16x8*)&sVt[(ctd * 16 + lm) * 264 + ch * 32 + lg * 8];
#pragma unroll
    for (int rt = 0; rt < 4; ++rt)
#pragma unroll
      for (int ctd = 0; ctd < 2; ++ctd)
        oacc[rt][ctd] = __builtin_amdgcn_mfma_f32_16x16x32_bf16(pf[rt], vf[ctd], oacc[rt][ctd], 0, 0, 0);
  }

  // softmax denominators: lane holds partial for i = rt*16+lm over its j quad;
  // reduce across the 4 quads (lanes lm, lm+16, lm+32, lm+48)
  float linv[4];
#pragma unroll
  for (int rt = 0; rt < 4; ++rt) {
    float v = lsum[rt];
    v += __shfl_xor(v, 16);
    v += __shfl_xor(v, 32);
    linv[rt] = 1.0f / v;
  }

  // normalize + store; O C-layout rows are i = rt*16 + lg*4 + r -> shfl the inverse
#pragma unroll
  for (int rt = 0; rt < 4; ++rt) {
#pragma unroll
    for (int r = 0; r < 4; ++r) {
      float inv = __shfl(linv[rt], jq + r);
      int i_g = w * 64 + rt * 16 + jq + r;
#pragma unroll
      for (int ctd = 0; ctd < 2; ++ctd) {
        float v = oacc[rt][ctd][r] * inv;
        u32 u = __builtin_bit_cast(u32, v) + 0x8000u;
        o_ws[((size_t)(n * 256 + i_g)) * 256 + h * 32 + ctd * 16 + lm] = (u16)(u >> 16);
      }
    }
  }
}

// ---------------- overlap-add combine: oc[t] = sum(covering o_ws)/cnt ----------------
__global__ void combine_kernel(const u16* __restrict__ o_ws, u16* __restrict__ oc) {
  int gid = blockIdx.x * 256 + threadIdx.x;
  int m = gid >> 5;             // global row (bc*4224 + t)
  int f0 = (gid & 31) << 3;     // 8 features per thread
  int bc = m / 4224;
  int t = m - bc * 4224;
  int i0 = t >> 7;
  float a[8] = {0.f, 0.f, 0.f, 0.f, 0.f, 0.f, 0.f, 0.f};
  if (i0 <= 31) {
    const u16* p = o_ws + ((size_t)((bc * 32 + i0) * 256 + (t - (i0 << 7)))) * 256 + f0;
    u32x4 v = *(const u32x4*)p;
#pragma unroll
    for (int q = 0; q < 4; ++q) {
      a[2 * q] += bf2f((u16)(v[q] & 0xFFFFu));
      a[2 * q + 1] += bf2f((u16)(v[q] >> 16));
    }
  }
  if (i0 >= 1) {
    int i1 = i0 - 1;
    const u16* p = o_ws + ((size_t)((bc * 32 + i1) * 256 + (t - (i1 << 7)))) * 256 + f0;
    u32x4 v = *(const u32x4*)p;
#pragma unroll
    for (int q = 0; q < 4; ++q) {
      a[2 * q] += bf2f((u16)(v[q] & 0xFFFFu));
      a[2 * q + 1] += bf2f((u16)(v[q] >> 16));
    }
  }
  float sc = (i0 >= 1 && i0 <= 31) ? 0.5f : 1.0f;
  u32x2 o;
  o[0] = (u32)f2bf(a[0] * sc) | ((u32)f2bf(a[1] * sc) << 16);
  o[1] = (u32)f2bf(a[2] * sc) | ((u32)f2bf(a[3] * sc) << 16);
  u32x2 o2;
  o2[0] = (u32)f2bf(a[4] * sc) | ((u32)f2bf(a[5] * sc) << 16);
  o2[1] = (u32)f2bf(a[6] * sc) | ((u32)f2bf(a[7] * sc) << 16);
  u16* dst = oc + (size_t)m * 256 + f0;
  *(u32x2*)dst = o;
  *(u32x2*)(dst + 4) = o2;
}

extern "C" void kernel_launch(void* const* d_in, const int* in_sizes, int n_in,
                              void* d_out, int out_size, void* d_ws, size_t ws_size,
                              hipStream_t stream) {
  const float* x = (const float*)d_in[0];
  const float* w_in = (const float*)d_in[1];
  const float* b_in = (const float*)d_in[2];
  const float* w_out = (const float*)d_in[3];
  const float* b_out = (const float*)d_in[4];
  float* y = (float*)d_out;
  char* ws = (char*)d_ws;

  // workspace layout (bytes)
  u16* qkv = (u16*)(ws);                   // 33792*768*2   = 51,904,512
  u16* xbf = (u16*)(ws + 51904512);        // 33792*256*2   = 17,301,504 (reused as oc)
  u16* ows = (u16*)(ws + 69206016);        // 256*256*256*2 = 33,554,432
  u16* winb = (u16*)(ws + 102760448);      // 768*256*2     = 393,216
  u16* woutb = (u16*)(ws + 103153664);     // 256*256*2     = 131,072  (end 103,284,736)

  cvt_kernel<<<8448, 256, 0, stream>>>(x, xbf, 2162688);
  cvt_kernel<<<192, 256, 0, stream>>>(w_in, winb, 49152);
  cvt_kernel<<<64, 256, 0, stream>>>(w_out, woutb, 16384);

  // qkv = x @ w_in^T + b_in  (once per row; overlapping blocks share rows)
  gemm_bt_kernel<true><<<dim3(264, 6), 256, 0, stream>>>(xbf, winb, b_in, qkv, 33792, 768, 256);

  // per-(block, head) attention
  attn_kernel<<<2048, 256, 0, stream>>>(qkv, ows);

  // overlap-add + count division (commutes with the linear w_out projection)
  combine_kernel<<<4224, 256, 0, stream>>>(ows, xbf);

  // y = oc @ w_out^T + b_out
  gemm_bt_kernel<false><<<dim3(264, 2), 256, 0, stream>>>(xbf, woutb, b_out, y, 33792, 256, 256);
}

// Round 7
// 185.377 us; speedup vs baseline: 2.1321x; 1.0204x over previous
//
#include <hip/hip_runtime.h>

typedef unsigned short u16;
typedef unsigned int u32;
typedef __attribute__((ext_vector_type(8))) short bf16x8;
typedef __attribute__((ext_vector_type(4))) float f32x4;
typedef __attribute__((ext_vector_type(4))) u32 u32x4;
typedef __attribute__((ext_vector_type(2))) u32 u32x2;

__device__ __forceinline__ u16 f2bf(float f) {
  u32 u = __builtin_bit_cast(u32, f);
  return (u16)((u + 0x7FFFu + ((u >> 16) & 1u)) >> 16);
}
__device__ __forceinline__ float bf2f(u16 b) {
  return __builtin_bit_cast(float, (u32)b << 16);
}

__device__ __forceinline__ float fexp2(float x) {
#if __has_builtin(__builtin_amdgcn_exp2f)
  return __builtin_amdgcn_exp2f(x);
#else
  return __expf(x * 0.6931471805599453f);
#endif
}

__device__ __forceinline__ void lds_async16(const void* g, void* l) {
  auto gp = reinterpret_cast<const __attribute__((address_space(1))) u32*>(
      reinterpret_cast<uintptr_t>(g));
  auto lp = reinterpret_cast<__attribute__((address_space(3))) u32*>(
      reinterpret_cast<uintptr_t>(l));
  __builtin_amdgcn_global_load_lds(gp, lp, 16, 0, 0);
}

// ---------------- fp32 -> bf16 convert (vec4) ----------------
__global__ void cvt_kernel(const float* __restrict__ in, u16* __restrict__ out, int n4) {
  int i = blockIdx.x * 256 + threadIdx.x;
  if (i < n4) {
    f32x4 v = *(const f32x4*)(in + (size_t)i * 4);
    u32x2 o;
    o[0] = (u32)f2bf(v[0]) | ((u32)f2bf(v[1]) << 16);
    o[1] = (u32)f2bf(v[2]) | ((u32)f2bf(v[3]) << 16);
    *(u32x2*)(out + (size_t)i * 4) = o;
  }
}

// two small weight converts in one launch (block 192 is exactly the boundary)
__global__ void cvt2_kernel(const float* __restrict__ a, const float* __restrict__ b,
                            u16* __restrict__ oa, u16* __restrict__ ob, int na4, int nb4) {
  int i = blockIdx.x * 256 + threadIdx.x;
  const float* src;
  u16* dst;
  int idx;
  if (i < na4) {
    src = a; dst = oa; idx = i;
  } else {
    idx = i - na4;
    if (idx >= nb4) return;
    src = b; dst = ob;
  }
  f32x4 v = *(const f32x4*)(src + (size_t)idx * 4);
  u32x2 o;
  o[0] = (u32)f2bf(v[0]) | ((u32)f2bf(v[1]) << 16);
  o[1] = (u32)f2bf(v[2]) | ((u32)f2bf(v[3]) << 16);
  *(u32x2*)(dst + (size_t)idx * 4) = o;
}

// ---------------- GEMM: C[m][n] = sum_k A[m][k]*B[n][k] + bias[n] ----------------
// EXACT round-4 version (proven passing). Round-5/6 operand swap mfma(bfr, af)
// with a vectorized epilogue produced absmax 1.01 in two clean A/B runs —
// reverted permanently. Do NOT swap the mfma operand order here.
template <bool OUT_BF16>
__global__ __launch_bounds__(256) void gemm_bt_kernel(
    const u16* __restrict__ A, const u16* __restrict__ B,
    const float* __restrict__ bias, void* __restrict__ C,
    int M, int N, int K) {
  __shared__ u16 sA[128 * 32];
  __shared__ u16 sB[128 * 32];
  const int tid = threadIdx.x;
  const int m0 = blockIdx.x * 128;
  const int n0 = blockIdx.y * 128;
  const int w = tid >> 6;
  const int lane = tid & 63;
  const int wr = (w >> 1) * 64;
  const int wc = (w & 1) * 64;
  const int lm = lane & 15;
  const int lk = (lane >> 4) * 8;

  f32x4 acc[4][4] = {};

  const int srow = tid >> 2;
  const int ssub = (tid & 3) * 8;
  const u16* Ag = A + (size_t)(m0 + srow) * K + ssub;
  const u16* Bg = B + (size_t)(n0 + srow) * K + ssub;
  const size_t rstep = (size_t)64 * K;

  for (int k0 = 0; k0 < K; k0 += 32) {
    __syncthreads();
    lds_async16(Ag + k0, &sA[tid * 8]);
    lds_async16(Ag + rstep + k0, &sA[2048 + tid * 8]);
    lds_async16(Bg + k0, &sB[tid * 8]);
    lds_async16(Bg + rstep + k0, &sB[2048 + tid * 8]);
    __syncthreads();
    bf16x8 af[4], bfr[4];
#pragma unroll
    for (int i = 0; i < 4; ++i)
      af[i] = *(const bf16x8*)&sA[(wr + i * 16 + lm) * 32 + lk];
#pragma unroll
    for (int j = 0; j < 4; ++j)
      bfr[j] = *(const bf16x8*)&sB[(wc + j * 16 + lm) * 32 + lk];
#pragma unroll
    for (int i = 0; i < 4; ++i)
#pragma unroll
      for (int j = 0; j < 4; ++j)
        acc[i][j] = __builtin_amdgcn_mfma_f32_16x16x32_bf16(af[i], bfr[j], acc[i][j], 0, 0, 0);
  }

  const int r0 = (lane >> 4) * 4;
#pragma unroll
  for (int j = 0; j < 4; ++j) {
    const int n = n0 + wc + j * 16 + lm;
    const float bv = bias[n];
#pragma unroll
    for (int i = 0; i < 4; ++i) {
#pragma unroll
      for (int r = 0; r < 4; ++r) {
        const int m = m0 + wr + i * 16 + r0 + r;
        float v = acc[i][j][r] + bv;
        if (OUT_BF16)
          ((u16*)C)[(size_t)m * N + n] = f2bf(v);
        else
          ((float*)C)[(size_t)m * N + n] = v;
      }
    }
  }
}

// ---------------- fused per-(block,head) attention ----------------
// qkv: 33792 x 768 bf16 (q|k|v each 256 cols). o_ws: (256 blocks x 256 rows x 256 f) bf16.
// S^T compute (mfma(K,Q)) so P regs are 4 consecutive j -> b64 LDS writes.
// PV done in two 32-row halves so the per-wave P tile is 32x40 u16:
// LDS = sVt 16896 + sP 10240 = 27136 B (r5/r6 absmax-identity exonerated this
// split: r6 failed identically WITHOUT it — the gemm swap was the bug).
// The asm memory fence pins the P-tile read -> overwrite (WAR) order the
// split introduces within one unrolled body.
// launch_bounds(256,2): (256,4) spilled catastrophically (r2). `#pragma unroll 1`
// on the ch loop is load-bearing: full unroll hoists all kf loads and spills (r3).
__global__ __launch_bounds__(256, 2) void attn_kernel(const u16* __restrict__ qkv,
                                                      u16* __restrict__ o_ws) {
  __shared__ u16 sVt[32 * 264];   // V transposed, stride 264 u16 (528B)
  __shared__ u16 sP[4 * 32 * 40]; // per-wave P half-tile: 32 rows x 40 u16

  const int bid = blockIdx.x;
  const int n = bid >> 3;
  const int h = bid & 7;
  const int rowbase = (n >> 5) * 4224 + (n & 31) * 128;
  const int tid = threadIdx.x;
  const int w = tid >> 6;
  const int lane = tid & 63;
  const int lm = lane & 15;
  const int lg = lane >> 4;

  // stage V transposed for this head
#pragma unroll
  for (int it = 0; it < 4; ++it) {
    int c = it * 256 + tid;
    int row = c >> 2;
    int sub = (c & 3) * 8;
    const u16* gv = qkv + (size_t)(rowbase + row) * 768 + 512 + h * 32 + sub;
    u32x4 vv = *(const u32x4*)gv;
#pragma unroll
    for (int q = 0; q < 4; ++q) {
      sVt[(sub + 2 * q) * 264 + row] = (u16)(vv[q] & 0xFFFFu);
      sVt[(sub + 2 * q + 1) * 264 + row] = (u16)(vv[q] >> 16);
    }
  }

  // Q fragments straight from global (wave-private rows; 16 rows x 64B contiguous)
  bf16x8 qf[4];
#pragma unroll
  for (int rt = 0; rt < 4; ++rt) {
    int row = rowbase + w * 64 + rt * 16 + lm;
    qf[rt] = *(const bf16x8*)(qkv + (size_t)row * 768 + h * 32 + lg * 8);
  }

  __syncthreads();

  f32x4 oacc[4][2] = {};
  float lsum[4] = {0.f, 0.f, 0.f, 0.f};
  u16* myP = sP + w * (32 * 40);
  const float C1 = 0.25500035370494726f; // scale * log2(e)
  const float C2 = 1.4426950408889634f;  // log2(e)
  const int jq = lg * 4;
  const u16* kbase = qkv + (size_t)(rowbase + lm) * 768 + 256 + h * 32 + lg * 8;
  const int D0w = w * 64;

#pragma unroll 1
  for (int ch = 0; ch < 8; ++ch) {
    bf16x8 kf[2], vf[2];
#pragma unroll
    for (int ct = 0; ct < 2; ++ct)
      kf[ct] = *(const bf16x8*)(kbase + (size_t)(ch * 32 + ct * 16) * 768);
#pragma unroll
    for (int ctd = 0; ctd < 2; ++ctd)
      vf[ctd] = *(const bf16x8*)&sVt[(ctd * 16 + lm) * 264 + ch * 32 + lg * 8];

#pragma unroll
    for (int hf = 0; hf < 2; ++hf) {
#pragma unroll
      for (int ct = 0; ct < 2; ++ct) {
#pragma unroll
        for (int rl = 0; rl < 2; ++rl) {
          const int rt = hf * 2 + rl;
          f32x4 s = __builtin_amdgcn_mfma_f32_16x16x32_bf16(kf[ct], qf[rt], f32x4{0.f, 0.f, 0.f, 0.f}, 0, 0, 0);
          const int D0 = D0w + rt * 16 - (ch * 32 + ct * 16); // wave-uniform
          float p0, p1, p2, p3;
          if (D0 >= 16 && D0 <= 112) {        // fully in-band: +1 bias
            p0 = fexp2(__builtin_fmaf(s[0], C1, C2));
            p1 = fexp2(__builtin_fmaf(s[1], C1, C2));
            p2 = fexp2(__builtin_fmaf(s[2], C1, C2));
            p3 = fexp2(__builtin_fmaf(s[3], C1, C2));
          } else if (D0 == 0) {               // diagonal: in-band iff lm >= jq+r
            p0 = fexp2(__builtin_fmaf(s[0], C1, (lm >= jq + 0) ? C2 : 0.0f));
            p1 = fexp2(__builtin_fmaf(s[1], C1, (lm >= jq + 1) ? C2 : 0.0f));
            p2 = fexp2(__builtin_fmaf(s[2], C1, (lm >= jq + 2) ? C2 : 0.0f));
            p3 = fexp2(__builtin_fmaf(s[3], C1, (lm >= jq + 3) ? C2 : 0.0f));
          } else if (D0 == 128) {             // far edge: in-band iff lm < jq+r
            p0 = fexp2(__builtin_fmaf(s[0], C1, (lm < jq + 0) ? C2 : 0.0f));
            p1 = fexp2(__builtin_fmaf(s[1], C1, (lm < jq + 1) ? C2 : 0.0f));
            p2 = fexp2(__builtin_fmaf(s[2], C1, (lm < jq + 2) ? C2 : 0.0f));
            p3 = fexp2(__builtin_fmaf(s[3], C1, (lm < jq + 3) ? C2 : 0.0f));
          } else {                            // fully out of band: no bias
            p0 = fexp2(s[0] * C1);
            p1 = fexp2(s[1] * C1);
            p2 = fexp2(s[2] * C1);
            p3 = fexp2(s[3] * C1);
          }
          lsum[rt] += (p0 + p1) + (p2 + p3);
          u32 u0 = __builtin_bit_cast(u32, p0) + 0x8000u;
          u32 u1 = __builtin_bit_cast(u32, p1) + 0x8000u;
          u32 u2 = __builtin_bit_cast(u32, p2) + 0x8000u;
          u32 u3 = __builtin_bit_cast(u32, p3) + 0x8000u;
          u32x2 pk;
          pk[0] = __builtin_amdgcn_perm(u1, u0, 0x07060302u);
          pk[1] = __builtin_amdgcn_perm(u3, u2, 0x07060302u);
          *(u32x2*)&myP[(rl * 16 + lm) * 40 + ct * 16 + jq] = pk;
        }
      }
      // O(half) += P(half) * Vc (wave-private P: in-order LDS per wave)
      bf16x8 pf[2];
#pragma unroll
      for (int rl = 0; rl < 2; ++rl)
        pf[rl] = *(const bf16x8*)&myP[(rl * 16 + lm) * 40 + lg * 8];
      // pin WAR order: these reads must precede the next half's overwrites
      __asm__ __volatile__("" ::: "memory");
#pragma unroll
      for (int rl = 0; rl < 2; ++rl)
#pragma unroll
        for (int ctd = 0; ctd < 2; ++ctd)
          oacc[hf * 2 + rl][ctd] =
              __builtin_amdgcn_mfma_f32_16x16x32_bf16(pf[rl], vf[ctd], oacc[hf * 2 + rl][ctd], 0, 0, 0);
    }
  }

  // softmax denominators: lane holds partial for i = rt*16+lm over its j quad;
  // reduce across the 4 quads (lanes lm, lm+16, lm+32, lm+48)
  float linv[4];
#pragma unroll
  for (int rt = 0; rt < 4; ++rt) {
    float v = lsum[rt];
    v += __shfl_xor(v, 16);
    v += __shfl_xor(v, 32);
    linv[rt] = 1.0f / v;
  }

  // normalize + store; O C-layout rows are i = rt*16 + lg*4 + r -> shfl the inverse
#pragma unroll
  for (int rt = 0; rt < 4; ++rt) {
#pragma unroll
    for (int r = 0; r < 4; ++r) {
      float inv = __shfl(linv[rt], jq + r);
      int i_g = w * 64 + rt * 16 + jq + r;
#pragma unroll
      for (int ctd = 0; ctd < 2; ++ctd) {
        float v = oacc[rt][ctd][r] * inv;
        u32 u = __builtin_bit_cast(u32, v) + 0x8000u;
        o_ws[((size_t)(n * 256 + i_g)) * 256 + h * 32 + ctd * 16 + lm] = (u16)(u >> 16);
      }
    }
  }
}

// ---------------- overlap-add combine: oc[t] = sum(covering o_ws)/cnt ----------------
__global__ void combine_kernel(const u16* __restrict__ o_ws, u16* __restrict__ oc) {
  int gid = blockIdx.x * 256 + threadIdx.x;
  int m = gid >> 5;             // global row (bc*4224 + t)
  int f0 = (gid & 31) << 3;     // 8 features per thread
  int bc = m / 4224;
  int t = m - bc * 4224;
  int i0 = t >> 7;
  float a[8] = {0.f, 0.f, 0.f, 0.f, 0.f, 0.f, 0.f, 0.f};
  if (i0 <= 31) {
    const u16* p = o_ws + ((size_t)((bc * 32 + i0) * 256 + (t - (i0 << 7)))) * 256 + f0;
    u32x4 v = *(const u32x4*)p;
#pragma unroll
    for (int q = 0; q < 4; ++q) {
      a[2 * q] += bf2f((u16)(v[q] & 0xFFFFu));
      a[2 * q + 1] += bf2f((u16)(v[q] >> 16));
    }
  }
  if (i0 >= 1) {
    int i1 = i0 - 1;
    const u16* p = o_ws + ((size_t)((bc * 32 + i1) * 256 + (t - (i1 << 7)))) * 256 + f0;
    u32x4 v = *(const u32x4*)p;
#pragma unroll
    for (int q = 0; q < 4; ++q) {
      a[2 * q] += bf2f((u16)(v[q] & 0xFFFFu));
      a[2 * q + 1] += bf2f((u16)(v[q] >> 16));
    }
  }
  float sc = (i0 >= 1 && i0 <= 31) ? 0.5f : 1.0f;
  u32x2 o;
  o[0] = (u32)f2bf(a[0] * sc) | ((u32)f2bf(a[1] * sc) << 16);
  o[1] = (u32)f2bf(a[2] * sc) | ((u32)f2bf(a[3] * sc) << 16);
  u32x2 o2;
  o2[0] = (u32)f2bf(a[4] * sc) | ((u32)f2bf(a[5] * sc) << 16);
  o2[1] = (u32)f2bf(a[6] * sc) | ((u32)f2bf(a[7] * sc) << 16);
  u16* dst = oc + (size_t)m * 256 + f0;
  *(u32x2*)dst = o;
  *(u32x2*)(dst + 4) = o2;
}

extern "C" void kernel_launch(void* const* d_in, const int* in_sizes, int n_in,
                              void* d_out, int out_size, void* d_ws, size_t ws_size,
                              hipStream_t stream) {
  const float* x = (const float*)d_in[0];
  const float* w_in = (const float*)d_in[1];
  const float* b_in = (const float*)d_in[2];
  const float* w_out = (const float*)d_in[3];
  const float* b_out = (const float*)d_in[4];
  float* y = (float*)d_out;
  char* ws = (char*)d_ws;

  // workspace layout (bytes)
  u16* qkv = (u16*)(ws);                   // 33792*768*2   = 51,904,512
  u16* xbf = (u16*)(ws + 51904512);        // 33792*256*2   = 17,301,504 (reused as oc)
  u16* ows = (u16*)(ws + 69206016);        // 256*256*256*2 = 33,554,432
  u16* winb = (u16*)(ws + 102760448);      // 768*256*2     = 393,216
  u16* woutb = (u16*)(ws + 103153664);     // 256*256*2     = 131,072  (end 103,284,736)

  cvt_kernel<<<8448, 256, 0, stream>>>(x, xbf, 2162688);
  cvt2_kernel<<<256, 256, 0, stream>>>(w_in, w_out, winb, woutb, 49152, 16384);

  // qkv = x @ w_in^T + b_in  (once per row; overlapping blocks share rows)
  gemm_bt_kernel<true><<<dim3(264, 6), 256, 0, stream>>>(xbf, winb, b_in, qkv, 33792, 768, 256);

  // per-(block, head) attention
  attn_kernel<<<2048, 256, 0, stream>>>(qkv, ows);

  // overlap-add + count division (commutes with the linear w_out projection)
  combine_kernel<<<4224, 256, 0, stream>>>(ows, xbf);

  // y = oc @ w_out^T + b_out
  gemm_bt_kernel<false><<<dim3(264, 2), 256, 0, stream>>>(xbf, woutb, b_out, y, 33792, 256, 256);
}